// Round 2
// baseline (274.547 us; speedup 1.0000x reference)
//
#include <hip/hip_runtime.h>

#define IMG 4096

// Token layout, derived from the reference's _build_token_layout():
//   level 0: 256 tokens, stride 1, 16x16 grid, offset 120 (grid units)
//   levels 1..4: 192 tokens each, stride 2^L, ring=4 layout, offset (256-16*2^L)/2
// pixel corner = 16 * (offset + stride * grid_coord)
__device__ __forceinline__ void token_info(int n, int& level, int& cx, int& cy) {
    int t, L;
    if (n < 256) { L = 0; t = n; }
    else { L = 1 + (n - 256) / 192; t = (n - 256) % 192; }
    int s = 1 << L;
    int offset = (256 - 16 * s) >> 1;  // grid units
    int x, y;
    if (L == 0) {
        x = t & 15; y = t >> 4;
    } else if (t < 64) {          // top 4 full rows
        y = t >> 4; x = t & 15;
    } else if (t < 128) {         // 8 middle rows: 4 left + 4 right
        int m = t - 64;
        y = 4 + (m >> 3);
        int j = m & 7;
        x = (j < 4) ? j : (8 + j);  // j=4..7 -> x=12..15
    } else {                      // bottom 4 full rows
        int m = t - 128;
        y = 12 + (m >> 4); x = m & 15;
    }
    level = L;
    cx = 16 * (offset + s * x);
    cy = 16 * (offset + s * y);
}

template <int S>
__device__ __forceinline__ int box_sum(const int* __restrict__ p) {
    int sum = 0;
#pragma unroll
    for (int r = 0; r < S; ++r) {
        const int* row = p + r * IMG;
        if constexpr (S >= 4) {
#pragma unroll
            for (int q = 0; q < S; q += 4) {
                int4 v = *(const int4*)(row + q);
                sum += v.x + v.y + v.z + v.w;
            }
        } else if constexpr (S == 2) {
            int2 v = *(const int2*)row;
            sum += v.x + v.y;
        } else {
            sum += *row;
        }
    }
    return sum;
}

__global__ __launch_bounds__(256) void Foveator_kernel(const int* __restrict__ img,
                                                       int* __restrict__ out) {
    // heavy-first (level 4 tokens have 256x the work of level 0)
    int id = 3071 - blockIdx.x;          // id = n*3 + c
    int n = id / 3;
    int c = id - 3 * n;

    int level, cx, cy;
    token_info(n, level, cx, cy);
    int s = 1 << level;

    int tid = threadIdx.x;
    int tx = tid & 15, ty = tid >> 4;

    const int* base = img + (size_t)c * IMG * IMG;
    const int* p = base + (size_t)(cy + s * ty) * IMG + (cx + s * tx);

    int sum;
    switch (level) {
        case 0: sum = box_sum<1>(p); break;
        case 1: sum = box_sum<2>(p); break;
        case 2: sum = box_sum<4>(p); break;
        case 3: sum = box_sum<8>(p); break;
        default: sum = box_sum<16>(p); break;
    }
    int val = sum >> (2 * level);        // floor(sum / s^2), sum >= 0

    out[(size_t)n * 768 + c * 256 + tid] = val;
}

extern "C" void kernel_launch(void* const* d_in, const int* in_sizes, int n_in,
                              void* d_out, int out_size, void* d_ws, size_t ws_size,
                              hipStream_t stream) {
    const int* img = (const int*)d_in[0];
    int* out = (int*)d_out;
    Foveator_kernel<<<dim3(3072), dim3(256), 0, stream>>>(img, out);
}

// Round 3
// 273.329 us; speedup vs baseline: 1.0045x; 1.0045x over previous
//
#include <hip/hip_runtime.h>

#define IMG 4096

// Token layout, derived from the reference's _build_token_layout():
//   level 0: 256 tokens, stride 1, 16x16 grid, offset 120 (grid units)
//   levels 1..4: 192 tokens each, stride 2^L, ring=4 layout, offset (256-16*2^L)/2
// pixel corner = 16 * (offset + stride * grid_coord)
__device__ __forceinline__ void token_info(int n, int& level, int& cx, int& cy) {
    int t, L;
    if (n < 256) { L = 0; t = n; }
    else { L = 1 + (n - 256) / 192; t = (n - 256) % 192; }
    int s = 1 << L;
    int offset = (256 - 16 * s) >> 1;  // grid units
    int x, y;
    if (L == 0) {
        x = t & 15; y = t >> 4;
    } else if (t < 64) {          // top 4 full rows
        y = t >> 4; x = t & 15;
    } else if (t < 128) {         // 8 middle rows: 4 left + 4 right
        int m = t - 64;
        y = 4 + (m >> 3);
        int j = m & 7;
        x = (j < 4) ? j : (8 + j);  // j=4..7 -> x=12..15
    } else {                      // bottom 4 full rows
        int m = t - 128;
        y = 12 + (m >> 4); x = m & 15;
    }
    level = L;
    cx = 16 * (offset + s * x);
    cy = 16 * (offset + s * y);
}

// Block-wide coalesced sweep of the (16s)x(16s) tile: 256 threads x int4 = 4KB
// (= 1024 px) per iteration, row-major. Each int4 lies inside one s-wide group
// for s>=4; partial sums accumulate into a 16x16 LDS grid.
template <int L>
__device__ __forceinline__ void process(const int* __restrict__ base, int cx, int cy,
                                        int* __restrict__ sAcc, int tid) {
    constexpr int S = 1 << L;
    constexpr int W = 16 * S;            // tile width in px
    constexpr int TOT = W * W;           // tile px
    constexpr int ITERS = (TOT + 1023) / 1024;
#pragma unroll
    for (int i = 0; i < ITERS; ++i) {
        int flat = i * 1024 + 4 * tid;   // px index within tile
        if constexpr (TOT < 1024) { if (flat >= TOT) break; }
        int r = flat / W;                // tile row (W is pow2 -> shift)
        int col = flat & (W - 1);        // tile col (multiple of 4)
        const int* p = base + (size_t)(cy + r) * IMG + (cx + col);
        int4 v = *(const int4*)p;
        int outrow = r >> L;
        if constexpr (S >= 4) {
            atomicAdd(&sAcc[outrow * 16 + (col >> L)], v.x + v.y + v.z + v.w);
        } else if constexpr (S == 2) {
            int g = col >> 1;            // col even -> px {col,col+1} in g, {col+2,col+3} in g+1
            atomicAdd(&sAcc[outrow * 16 + g], v.x + v.y);
            atomicAdd(&sAcc[outrow * 16 + g + 1], v.z + v.w);
        } else {                         // S == 1: each px is its own output
            sAcc[outrow * 16 + col + 0] = v.x;
            sAcc[outrow * 16 + col + 1] = v.y;
            sAcc[outrow * 16 + col + 2] = v.z;
            sAcc[outrow * 16 + col + 3] = v.w;
        }
    }
}

__global__ __launch_bounds__(256) void Foveator_kernel(const int* __restrict__ img,
                                                       int* __restrict__ out) {
    // heavy-first (level 4 tokens have 256x the work of level 0)
    int id = 3071 - blockIdx.x;          // id = n*3 + c
    int n = id / 3;
    int c = id - 3 * n;

    int level, cx, cy;
    token_info(n, level, cx, cy);

    __shared__ int sAcc[256];
    int tid = threadIdx.x;
    sAcc[tid] = 0;
    __syncthreads();

    const int* base = img + (size_t)c * IMG * IMG;
    switch (level) {
        case 0: process<0>(base, cx, cy, sAcc, tid); break;
        case 1: process<1>(base, cx, cy, sAcc, tid); break;
        case 2: process<2>(base, cx, cy, sAcc, tid); break;
        case 3: process<3>(base, cx, cy, sAcc, tid); break;
        default: process<4>(base, cx, cy, sAcc, tid); break;
    }
    __syncthreads();

    out[(size_t)n * 768 + c * 256 + tid] = sAcc[tid] >> (2 * level);
}

extern "C" void kernel_launch(void* const* d_in, const int* in_sizes, int n_in,
                              void* d_out, int out_size, void* d_ws, size_t ws_size,
                              hipStream_t stream) {
    const int* img = (const int*)d_in[0];
    int* out = (int*)d_out;
    Foveator_kernel<<<dim3(3072), dim3(256), 0, stream>>>(img, out);
}

// Round 4
// 264.809 us; speedup vs baseline: 1.0368x; 1.0322x over previous
//
#include <hip/hip_runtime.h>

#define IMG 4096

// Token layout, derived from the reference's _build_token_layout():
//   level 0: 256 tokens, stride 1, 16x16 grid, offset 120 (grid units)
//   levels 1..4: 192 tokens each, stride 2^L, ring=4 layout, offset (256-16*2^L)/2
// pixel corner = 16 * (offset + stride * grid_coord). Verified absmax=0 in R2/R3.
__device__ __forceinline__ void token_info(int n, int& level, int& cx, int& cy) {
    int t, L;
    if (n < 256) { L = 0; t = n; }
    else { L = 1 + (n - 256) / 192; t = (n - 256) % 192; }
    int s = 1 << L;
    int offset = (256 - 16 * s) >> 1;  // grid units
    int x, y;
    if (L == 0) {
        x = t & 15; y = t >> 4;
    } else if (t < 64) {          // top 4 full rows
        y = t >> 4; x = t & 15;
    } else if (t < 128) {         // 8 middle rows: 4 left + 4 right
        int m = t - 64;
        y = 4 + (m >> 3);
        int j = m & 7;
        x = (j < 4) ? j : (8 + j);  // j=4..7 -> x=12..15
    } else {                      // bottom 4 full rows
        int m = t - 128;
        y = 12 + (m >> 4); x = m & 15;
    }
    level = L;
    cx = 16 * (offset + s * x);
    cy = 16 * (offset + s * y);
}

// Block = 4 waves = one (token, channel, outrow-quad). Each wave owns one of
// the 16 output rows: contiguous int4 wave loads over the S tile rows of that
// output row, register accumulate, 2x shfl_xor reduce, 16 writer lanes store
// straight to global. No LDS, no atomics, no __syncthreads.
__global__ __launch_bounds__(256) void Foveator_kernel(const int* __restrict__ img,
                                                       int* __restrict__ out) {
    int rid = 12287 - (int)blockIdx.x;   // heavy (level-4) blocks first
    int n = rid / 12;                    // token 0..1023
    int rem = rid - 12 * n;
    int c = rem >> 2;                    // channel 0..2
    int q = rem & 3;                     // outrow quad 0..3

    int level, cx, cy;
    token_info(n, level, cx, cy);

    int tid = threadIdx.x;
    int lane = tid & 63;
    int o = 4 * q + (tid >> 6);          // output row 0..15 (one per wave)

    const int* base = img + (size_t)c * IMG * IMG;
    int* obase = out + n * 768 + c * 256 + o * 16;

    switch (level) {
        case 4: {  // box 16x16, tile row = 256 px = one full wave-load
            const int* p = base + (size_t)(cy + 16 * o) * IMG + cx + 4 * lane;
            int sum = 0;
#pragma unroll
            for (int t = 0; t < 16; ++t) {
                int4 v = *(const int4*)(p + (size_t)t * IMG);
                sum += v.x + v.y + v.z + v.w;
            }
            sum += __shfl_xor(sum, 1, 64);   // lanes 4k..4k+3 share outcol k
            sum += __shfl_xor(sum, 2, 64);
            if ((lane & 3) == 0) obase[lane >> 2] = sum >> 8;
        } break;
        case 3: {  // box 8x8, wave-load covers 2 tile rows of 128 px
            const int* p = base + (size_t)(cy + 8 * o + (lane >> 5)) * IMG + cx + 4 * (lane & 31);
            int sum = 0;
#pragma unroll
            for (int t = 0; t < 4; ++t) {
                int4 v = *(const int4*)(p + (size_t)(2 * t) * IMG);
                sum += v.x + v.y + v.z + v.w;
            }
            sum += __shfl_xor(sum, 1, 64);   // {2k,2k+1} same outcol
            sum += __shfl_xor(sum, 32, 64);  // combine the two row-halves
            if (lane < 32 && (lane & 1) == 0) obase[lane >> 1] = sum >> 6;
        } break;
        case 2: {  // box 4x4, one wave-load covers all 4 tile rows of 64 px
            const int* p = base + (size_t)(cy + 4 * o + (lane >> 4)) * IMG + cx + 4 * (lane & 15);
            int4 v = *(const int4*)p;
            int sum = v.x + v.y + v.z + v.w;
            sum += __shfl_xor(sum, 16, 64);  // {k,k+16,k+32,k+48} same outcol
            sum += __shfl_xor(sum, 32, 64);
            if (lane < 16) obase[lane] = sum >> 4;
        } break;
        case 1: {  // box 2x2, 2 tile rows x 32 px = 16 active lanes
            if (lane < 16) {
                const int* p = base + (size_t)(cy + 2 * o + (lane >> 3)) * IMG + cx + 4 * (lane & 7);
                int4 v = *(const int4*)p;
                int a = v.x + v.y, b = v.z + v.w;   // two adjacent boxes
                a += __shfl_xor(a, 8, 64);          // combine the two rows
                b += __shfl_xor(b, 8, 64);
                if (lane < 8) { obase[2 * lane] = a >> 2; obase[2 * lane + 1] = b >> 2; }
            }
        } break;
        default: {  // level 0: box 1x1 -> straight copy of one 16-px row
            if (lane < 4) {
                const int* p = base + (size_t)(cy + o) * IMG + cx + 4 * lane;
                *(int4*)(obase + 4 * lane) = *(const int4*)p;
            }
        } break;
    }
}

extern "C" void kernel_launch(void* const* d_in, const int* in_sizes, int n_in,
                              void* d_out, int out_size, void* d_ws, size_t ws_size,
                              hipStream_t stream) {
    const int* img = (const int*)d_in[0];
    int* out = (int*)d_out;
    Foveator_kernel<<<dim3(12288), dim3(256), 0, stream>>>(img, out);
}

// Round 6
// 253.698 us; speedup vs baseline: 1.0822x; 1.0438x over previous
//
#include <hip/hip_runtime.h>

#define IMG 4096

typedef int v4i __attribute__((ext_vector_type(4)));

// Token layout, derived from the reference's _build_token_layout():
//   level 0: 256 tokens, stride 1, 16x16 grid, offset 120 (grid units)
//   levels 1..4: 192 tokens each, stride 2^L, ring=4 layout, offset (256-16*2^L)/2
// pixel corner = 16 * (offset + stride * grid_coord). Verified absmax=0 in R2-R4.
__device__ __forceinline__ void token_info(int n, int& level, int& cx, int& cy) {
    int t, L;
    if (n < 256) { L = 0; t = n; }
    else { L = 1 + (n - 256) / 192; t = (n - 256) % 192; }
    int s = 1 << L;
    int offset = (256 - 16 * s) >> 1;  // grid units
    int x, y;
    if (L == 0) {
        x = t & 15; y = t >> 4;
    } else if (t < 64) {          // top 4 full rows
        y = t >> 4; x = t & 15;
    } else if (t < 128) {         // 8 middle rows: 4 left + 4 right
        int m = t - 64;
        y = 4 + (m >> 3);
        int j = m & 7;
        x = (j < 4) ? j : (8 + j);  // j=4..7 -> x=12..15
    } else {                      // bottom 4 full rows
        int m = t - 128;
        y = 12 + (m >> 4); x = m & 15;
    }
    level = L;
    cx = 16 * (offset + s * x);
    cy = 16 * (offset + s * y);
}

__device__ __forceinline__ v4i nt_load4(const int* p) {
    return __builtin_nontemporal_load((const v4i*)p);
}

// Block = 4 waves = one (token, channel, outrow-quad). Each wave owns one of
// the 16 output rows: contiguous int4 nontemporal wave loads over the S tile
// rows of that output row, register accumulate, shfl_xor reduce, writer lanes
// store straight to global. No LDS, no atomics, no __syncthreads. Input is
// read-once (levels tile the image disjointly) -> nt loads avoid polluting
// L2/LLC that is busy draining the harness's 768MiB poison fill.
__global__ __launch_bounds__(256) void Foveator_kernel(const int* __restrict__ img,
                                                       int* __restrict__ out) {
    int rid = 12287 - (int)blockIdx.x;   // heavy (level-4) blocks first
    int n = rid / 12;                    // token 0..1023
    int rem = rid - 12 * n;
    int c = rem >> 2;                    // channel 0..2
    int q = rem & 3;                     // outrow quad 0..3

    int level, cx, cy;
    token_info(n, level, cx, cy);

    int tid = threadIdx.x;
    int lane = tid & 63;
    int o = 4 * q + (tid >> 6);          // output row 0..15 (one per wave)

    const int* base = img + (size_t)c * IMG * IMG;
    int* obase = out + n * 768 + c * 256 + o * 16;

    switch (level) {
        case 4: {  // box 16x16, tile row = 256 px = one full wave-load
            const int* p = base + (size_t)(cy + 16 * o) * IMG + cx + 4 * lane;
            int s0 = 0, s1 = 0;
#pragma unroll
            for (int t = 0; t < 16; t += 2) {
                v4i v0 = nt_load4(p + (size_t)t * IMG);
                v4i v1 = nt_load4(p + (size_t)(t + 1) * IMG);
                s0 += v0.x + v0.y + v0.z + v0.w;
                s1 += v1.x + v1.y + v1.z + v1.w;
            }
            int sum = s0 + s1;
            sum += __shfl_xor(sum, 1, 64);   // lanes 4k..4k+3 share outcol k
            sum += __shfl_xor(sum, 2, 64);
            if ((lane & 3) == 0)
                __builtin_nontemporal_store(sum >> 8, &obase[lane >> 2]);
        } break;
        case 3: {  // box 8x8, wave-load covers 2 tile rows of 128 px
            const int* p = base + (size_t)(cy + 8 * o + (lane >> 5)) * IMG + cx + 4 * (lane & 31);
            int sum = 0;
#pragma unroll
            for (int t = 0; t < 4; ++t) {
                v4i v = nt_load4(p + (size_t)(2 * t) * IMG);
                sum += v.x + v.y + v.z + v.w;
            }
            sum += __shfl_xor(sum, 1, 64);   // {2k,2k+1} same outcol
            sum += __shfl_xor(sum, 32, 64);  // combine the two row-halves
            if (lane < 32 && (lane & 1) == 0)
                __builtin_nontemporal_store(sum >> 6, &obase[lane >> 1]);
        } break;
        case 2: {  // box 4x4, one wave-load covers all 4 tile rows of 64 px
            const int* p = base + (size_t)(cy + 4 * o + (lane >> 4)) * IMG + cx + 4 * (lane & 15);
            v4i v = nt_load4(p);
            int sum = v.x + v.y + v.z + v.w;
            sum += __shfl_xor(sum, 16, 64);  // {k,k+16,k+32,k+48} same outcol
            sum += __shfl_xor(sum, 32, 64);
            if (lane < 16)
                __builtin_nontemporal_store(sum >> 4, &obase[lane]);
        } break;
        case 1: {  // box 2x2, 2 tile rows x 32 px = 16 active lanes
            if (lane < 16) {
                const int* p = base + (size_t)(cy + 2 * o + (lane >> 3)) * IMG + cx + 4 * (lane & 7);
                v4i v = nt_load4(p);
                int a = v.x + v.y, b = v.z + v.w;   // two adjacent boxes
                a += __shfl_xor(a, 8, 64);          // combine the two rows
                b += __shfl_xor(b, 8, 64);
                if (lane < 8) {
                    __builtin_nontemporal_store(a >> 2, &obase[2 * lane]);
                    __builtin_nontemporal_store(b >> 2, &obase[2 * lane + 1]);
                }
            }
        } break;
        default: {  // level 0: box 1x1 -> straight copy of one 16-px row
            if (lane < 4) {
                const int* p = base + (size_t)(cy + o) * IMG + cx + 4 * lane;
                v4i v = nt_load4(p);
                __builtin_nontemporal_store(v, (v4i*)(obase + 4 * lane));
            }
        } break;
    }
}

extern "C" void kernel_launch(void* const* d_in, const int* in_sizes, int n_in,
                              void* d_out, int out_size, void* d_ws, size_t ws_size,
                              hipStream_t stream) {
    const int* img = (const int*)d_in[0];
    int* out = (int*)d_out;
    Foveator_kernel<<<dim3(12288), dim3(256), 0, stream>>>(img, out);
}